// Round 14
// baseline (37.116 us; speedup 1.0000x reference)
//
#include <hip/hip_runtime.h>

typedef unsigned short ushort_t;
typedef __bf16 bf16x8 __attribute__((ext_vector_type(8)));
typedef float f32x4 __attribute__((ext_vector_type(4)));
typedef ushort_t ushort8 __attribute__((ext_vector_type(8)));

static __device__ __forceinline__ ushort_t f2bf(float f) {
    __bf16 b = (__bf16)f;   // RNE convert
    return __builtin_bit_cast(ushort_t, b);
}

#define GLOAD_LDS16(gptr, lptr)                                                        \
    __builtin_amdgcn_global_load_lds(                                                  \
        (const __attribute__((address_space(1))) void*)(gptr),                         \
        (__attribute__((address_space(3))) void*)(lptr), 16, 0, 0)

#define CFENCE() asm volatile("" ::: "memory")
#define LGKM0_SCHED() do { asm volatile("s_waitcnt lgkmcnt(0)" ::: "memory");          \
                           __builtin_amdgcn_sched_barrier(0); } while (0)

template <int N> __device__ __forceinline__ void waitcnt_vm() {
    if constexpr (N == 0)       asm volatile("s_waitcnt vmcnt(0)" ::: "memory");
    else if constexpr (N == 4)  asm volatile("s_waitcnt vmcnt(4)" ::: "memory");
    else if constexpr (N == 8)  asm volatile("s_waitcnt vmcnt(8)" ::: "memory");
}

// ---------------------------------------------------------------------------
// Triple-buffered, bank-conflict-free GEMM core (r8-proven, UNCHANGED —
// used by k2's gemm1). C = A @ B^T (+bias), bf16 in. BK=64.
// LDS: lds[row*64 + s*8..+8) = tile[row][(s^(row&7))*8..+8).
template <int BM, int BN, int WGM, int WGN, int THREADS, bool BF16_OUT>
__device__ __forceinline__
void gemm_core64(const ushort_t* __restrict__ A, const ushort_t* __restrict__ B,
                 const float* __restrict__ bias, void* __restrict__ C,
                 const int K, const int N, const int rA, const int rB,
                 ushort_t* ls) {
    constexpr int WM = BM / WGM, WN = BN / WGN;
    constexpr int MI = WM / 16, NJ = WN / 16;
    constexpr int LA = (BM * 8) / THREADS;
    constexpr int LB = (BN * 8) / THREADS;
    constexpr int L  = LA + LB;
    constexpr int HALF = (BM + BN) * 64;

    const int tid  = threadIdx.x;
    const int lane = tid & 63;
    const int wv   = tid >> 6;
    const int wr   = wv / WGN, wc = wv % WGN;
    const int fr   = lane & 15, fq = lane >> 4;

    f32x4 acc[MI][NJ] = {};

    auto stage = [&](int k0, int buf) {
        #pragma unroll
        for (int q = 0; q < LA; ++q) {
            int c = q * THREADS + tid;
            int row = c >> 3;
            int u = (c & 7) ^ (row & 7);
            GLOAD_LDS16(A + (size_t)(rA + row) * K + k0 + u * 8,
                        &ls[buf * HALF + c * 8]);
        }
        #pragma unroll
        for (int q = 0; q < LB; ++q) {
            int c = q * THREADS + tid;
            int row = c >> 3;
            int u = (c & 7) ^ (row & 7);
            GLOAD_LDS16(B + (size_t)(rB + row) * K + k0 + u * 8,
                        &ls[buf * HALF + BM * 64 + c * 8]);
        }
    };

    auto compute = [&](int buf) {
        #pragma unroll
        for (int sub = 0; sub < 2; ++sub) {
            const int u = sub * 4 + fq;
            bf16x8 af[MI], bfv[NJ];
            #pragma unroll
            for (int i = 0; i < MI; ++i) {
                const int row = wr * WM + i * 16 + fr;
                af[i] = *(const bf16x8*)&ls[buf * HALF + row * 64 + (u ^ (row & 7)) * 8];
            }
            #pragma unroll
            for (int j = 0; j < NJ; ++j) {
                const int row = wc * WN + j * 16 + fr;
                bfv[j] = *(const bf16x8*)&ls[buf * HALF + BM * 64 + row * 64 + (u ^ (row & 7)) * 8];
            }
            #pragma unroll
            for (int i = 0; i < MI; ++i)
                #pragma unroll
                for (int j = 0; j < NJ; ++j)
                    acc[i][j] = __builtin_amdgcn_mfma_f32_16x16x32_bf16(af[i], bfv[j], acc[i][j], 0, 0, 0);
        }
    };

    const int T = K >> 6;
    stage(0, 0);
    stage(64, 1);
    int cur = 0, nxt2 = 2;
    for (int t = 0; t < T - 2; ++t) {
        stage((t + 2) << 6, nxt2);
        waitcnt_vm<2 * L>();
        __builtin_amdgcn_s_barrier(); CFENCE();
        compute(cur);
        LGKM0_SCHED();
        __builtin_amdgcn_s_barrier(); CFENCE();
        cur  = (cur  + 1 == 3) ? 0 : cur  + 1;
        nxt2 = (nxt2 + 1 == 3) ? 0 : nxt2 + 1;
    }
    waitcnt_vm<L>();
    __builtin_amdgcn_s_barrier(); CFENCE();
    compute(cur);
    cur = (cur + 1 == 3) ? 0 : cur + 1;
    LGKM0_SCHED();
    waitcnt_vm<0>();
    __builtin_amdgcn_s_barrier(); CFENCE();
    compute(cur);

    const int orow0 = rA + wr * WM + fq * 4;
    const int ocol0 = rB + wc * WN + fr;
    #pragma unroll
    for (int i = 0; i < MI; ++i)
        #pragma unroll
        for (int j = 0; j < NJ; ++j) {
            const int col = ocol0 + j * 16;
            const float bv = bias ? bias[col] : 0.f;
            #pragma unroll
            for (int r = 0; r < 4; ++r) {
                const int row = orow0 + i * 16 + r;
                const float v = acc[i][j][r] + bv;
                if constexpr (BF16_OUT)
                    ((ushort_t*)C)[(size_t)row * N + col] = f2bf(v);
                else
                    ((float*)C)[(size_t)row * N + col] = v;
            }
        }
}

// ---------------------------------------------------------------------------
// L1 prep: [0,128): w_out->bf16; [128,384): Pt[c][j] = bf16(w_in[r(j)][c]);
//          [384,640): bfused rows (independent of other prep outputs).
__global__ __launch_bounds__(256)
void prep(const float* __restrict__ w_in, const float* __restrict__ w_out,
          const float* __restrict__ b_in, const float* __restrict__ b_out,
          ushort_t* __restrict__ wob, ushort_t* __restrict__ Pt,
          float* __restrict__ bfused) {
    __shared__ ushort_t tile[64][65];
    const int b = blockIdx.x;
    const int t = threadIdx.x;

    if (b < 128) {
        #pragma unroll
        for (int p = 0; p < 8; ++p) {
            int i = b * 2048 + p * 256 + t;
            float4 v = ((const float4*)w_out)[i];
            ushort4 o; o.x = f2bf(v.x); o.y = f2bf(v.y); o.z = f2bf(v.z); o.w = f2bf(v.w);
            ((ushort4*)wob)[i] = o;
        }
    } else if (b < 384) {
        const int g = b - 128;
        const int gx = g & 15, gy = g >> 4;
        #pragma unroll
        for (int p = 0; p < 16; ++p) {
            int e = p * 256 + t;
            int j = e >> 6, c = e & 63;
            tile[j][c] = f2bf(w_in[(size_t)(gx * 192 + 128 + j) * 1024 + gy * 64 + c]);
        }
        __syncthreads();
        #pragma unroll
        for (int p = 0; p < 16; ++p) {
            int e = p * 256 + t;
            int c = e >> 6, j = e & 63;
            Pt[(size_t)(gy * 64 + c) * 1024 + gx * 64 + j] = tile[j][c];
        }
    } else {
        const int w = t >> 6, lane = t & 63;
        const int row = (b - 384) * 4 + w;
        float s = 0.f;
        #pragma unroll
        for (int it = 0; it < 16; ++it) {
            int j = it * 64 + lane;
            int r = (j >> 6) * 192 + 128 + (j & 63);
            s += w_out[(size_t)row * 1024 + j] * b_in[r];
        }
        #pragma unroll
        for (int off = 32; off; off >>= 1) s += __shfl_down(s, off, 64);
        if (lane == 0) bfused[row] = s + b_out[row];
    }
}

// ---------------------------------------------------------------------------
// L2: gemm1 only — Wf = wob @ Pt^T (64x64 tiles, XCD-swizzled, r8 core).
__global__ __launch_bounds__(256)
void k2(const ushort_t* __restrict__ wob, const ushort_t* __restrict__ Pt,
        ushort_t* __restrict__ Wfb) {
    __shared__ alignas(16) ushort_t ls[3 * (64 + 64) * 64];
    const int b = blockIdx.x;
    const int swz = (b & 7) * 32 + (b >> 3);
    const int by = swz >> 4, bx = swz & 15;
    gemm_core64<64, 64, 2, 2, 256, true>(wob, Pt, nullptr, (void*)Wfb, 1024, 1024,
                                         by * 64, bx * 64, ls);
}

// ---------------------------------------------------------------------------
// L3: out = x @ Wfb^T + bfused, A staged DIRECTLY FROM FP32 x (reg path:
//     global float4 x4 -> 8x f2bf -> swizzled ushort8 ds_write; same LDS
//     image as global_load_lds staging). B via global_load_lds. T14 order:
//     issue loads BEFORE compute, convert+write AFTER. Double-buffered,
//     64 KB LDS -> 2 blocks/CU. 128x128 tiles, 8 waves 2x4, XCD-swizzled.
__global__ __launch_bounds__(512, 4)
void k3(const float* __restrict__ x, const ushort_t* __restrict__ Wfb,
        const float* __restrict__ bfused, float* __restrict__ out) {
    constexpr int HALF = 16384;                     // A 8192 + B 8192 ushorts
    __shared__ alignas(16) ushort_t ls[2 * HALF];   // 64 KB
    const int b = blockIdx.x;
    const int swz = (b & 7) * 32 + (b >> 3);
    const int by = swz >> 3, bx = swz & 7;          // 32 M-tiles x 8 N-tiles
    const int rA = by * 128, rB = bx * 128;

    const int tid  = threadIdx.x;
    const int lane = tid & 63;
    const int wv   = tid >> 6;
    const int wr   = wv >> 2, wc = wv & 3;          // 2x4 waves: WM=64, WN=32
    const int fr   = lane & 15, fq = lane >> 4;

    float4 rg[4];
    auto aload = [&](int k0) {
        #pragma unroll
        for (int q = 0; q < 2; ++q) {
            int c = q * 512 + tid; int row = c >> 3; int u = (c & 7) ^ (row & 7);
            const float* p = x + (size_t)(rA + row) * 1024 + k0 + u * 8;
            rg[q * 2 + 0] = ((const float4*)p)[0];
            rg[q * 2 + 1] = ((const float4*)p)[1];
        }
    };
    auto awrite = [&](int buf) {
        #pragma unroll
        for (int q = 0; q < 2; ++q) {
            int c = q * 512 + tid;
            const float4 v0 = rg[q * 2], v1 = rg[q * 2 + 1];
            ushort8 o;
            o[0]=f2bf(v0.x); o[1]=f2bf(v0.y); o[2]=f2bf(v0.z); o[3]=f2bf(v0.w);
            o[4]=f2bf(v1.x); o[5]=f2bf(v1.y); o[6]=f2bf(v1.z); o[7]=f2bf(v1.w);
            *(ushort8*)&ls[buf * HALF + c * 8] = o;
        }
    };
    auto bstage = [&](int k0, int buf) {
        #pragma unroll
        for (int q = 0; q < 2; ++q) {
            int c = q * 512 + tid; int row = c >> 3; int u = (c & 7) ^ (row & 7);
            GLOAD_LDS16(Wfb + (size_t)(rB + row) * 1024 + k0 + u * 8,
                        &ls[buf * HALF + 8192 + c * 8]);
        }
    };

    f32x4 acc[4][2] = {};
    auto compute = [&](int buf) {
        #pragma unroll
        for (int sub = 0; sub < 2; ++sub) {
            const int u = sub * 4 + fq;
            bf16x8 af[4], bfv[2];
            #pragma unroll
            for (int i = 0; i < 4; ++i) {
                const int row = wr * 64 + i * 16 + fr;
                af[i] = *(const bf16x8*)&ls[buf * HALF + row * 64 + (u ^ (row & 7)) * 8];
            }
            #pragma unroll
            for (int j = 0; j < 2; ++j) {
                const int row = wc * 32 + j * 16 + fr;
                bfv[j] = *(const bf16x8*)&ls[buf * HALF + 8192 + row * 64 + (u ^ (row & 7)) * 8];
            }
            #pragma unroll
            for (int i = 0; i < 4; ++i)
                #pragma unroll
                for (int j = 0; j < 2; ++j)
                    acc[i][j] = __builtin_amdgcn_mfma_f32_16x16x32_bf16(af[i], bfv[j], acc[i][j], 0, 0, 0);
        }
    };

    // prologue: tile 0 fully staged
    aload(0);                      // R4 in flight
    bstage(0, 0);                  // B2 in flight
    awrite(0);                     // compiler waits R4 (vmcnt(2)), B stays in flight
    LGKM0_SCHED();
    waitcnt_vm<0>();               // B0 landed
    __builtin_amdgcn_s_barrier(); CFENCE();

    for (int t = 0; t < 16; ++t) {
        const int cur = t & 1;
        if (t < 15) {
            aload((t + 1) << 6);             // issue A(t+1) loads (R4)
            bstage((t + 1) << 6, cur ^ 1);   // issue B(t+1) (B2, after R4)
        }
        compute(cur);                        // ~600 cy of cover for the loads
        if (t < 15) {
            awrite(cur ^ 1);                 // waits R4 only (vmcnt(2) auto)
            LGKM0_SCHED();                   // my ds_writes + ds_reads drained
            waitcnt_vm<0>();                 // B(t+1) landed (latency covered)
            __builtin_amdgcn_s_barrier(); CFENCE();
        }
    }

    const int orow0 = rA + wr * 64 + fq * 4;
    const int ocol0 = rB + wc * 32 + fr;
    #pragma unroll
    for (int i = 0; i < 4; ++i)
        #pragma unroll
        for (int j = 0; j < 2; ++j) {
            const int col = ocol0 + j * 16;
            const float bv = bfused[col];
            #pragma unroll
            for (int r = 0; r < 4; ++r)
                out[(size_t)(orow0 + i * 16 + r) * 1024 + col] = acc[i][j][r] + bv;
        }
}

// ---------------------------------------------------------------------------
extern "C" void kernel_launch(void* const* d_in, const int* in_sizes, int n_in,
                              void* d_out, int out_size, void* d_ws, size_t ws_size,
                              hipStream_t stream) {
    const float* x     = (const float*)d_in[0];   // (2,2048,1024)
    const float* w_in  = (const float*)d_in[1];   // (3072,1024)
    const float* b_in  = (const float*)d_in[2];   // (3072,)
    const float* w_out = (const float*)d_in[3];   // (1024,1024)
    const float* b_out = (const float*)d_in[4];   // (1024,)
    float* out = (float*)d_out;                   // (2,2048,1024) fp32

    char* ws = (char*)d_ws;
    ushort_t* wob    = (ushort_t*)(ws);                      // 2 MB
    ushort_t* Pt     = (ushort_t*)(ws + (2u << 20));         // 2 MB
    ushort_t* Wfb    = (ushort_t*)(ws + (4u << 20));         // 2 MB
    float*    bfused = (float*)   (ws + (6u << 20));         // 4 KB

    prep<<<640, 256, 0, stream>>>(w_in, w_out, b_in, b_out, wob, Pt, bfused);
    k2<<<256, 256, 0, stream>>>(wob, Pt, Wfb);
    k3<<<256, 512, 0, stream>>>(x, Wfb, bfused, out);
}

// Round 15
// 33.956 us; speedup vs baseline: 1.0931x; 1.0931x over previous
//
#include <hip/hip_runtime.h>

typedef unsigned short ushort_t;
typedef __bf16 bf16x8 __attribute__((ext_vector_type(8)));
typedef float f32x4 __attribute__((ext_vector_type(4)));

static __device__ __forceinline__ ushort_t f2bf(float f) {
    __bf16 b = (__bf16)f;   // RNE convert
    return __builtin_bit_cast(ushort_t, b);
}

#define GLOAD_LDS16(gptr, lptr)                                                        \
    __builtin_amdgcn_global_load_lds(                                                  \
        (const __attribute__((address_space(1))) void*)(gptr),                         \
        (__attribute__((address_space(3))) void*)(lptr), 16, 0, 0)

#define CFENCE() asm volatile("" ::: "memory")
#define LGKM0_SCHED() do { asm volatile("s_waitcnt lgkmcnt(0)" ::: "memory");          \
                           __builtin_amdgcn_sched_barrier(0); } while (0)

template <int N> __device__ __forceinline__ void waitcnt_vm() {
    if constexpr (N == 0)       asm volatile("s_waitcnt vmcnt(0)" ::: "memory");
    else if constexpr (N == 4)  asm volatile("s_waitcnt vmcnt(4)" ::: "memory");
    else if constexpr (N == 8)  asm volatile("s_waitcnt vmcnt(8)" ::: "memory");
}

// ---------------------------------------------------------------------------
// Triple-buffered, bank-conflict-free GEMM core, BK=64 (r8-proven, UNCHANGED —
// used by k2's gemm1). C = A @ B^T (+bias), bf16 in.
// LDS: lds[row*64 + s*8..+8) = tile[row][(s^(row&7))*8..+8).
template <int BM, int BN, int WGM, int WGN, int THREADS, bool BF16_OUT>
__device__ __forceinline__
void gemm_core64(const ushort_t* __restrict__ A, const ushort_t* __restrict__ B,
                 const float* __restrict__ bias, void* __restrict__ C,
                 const int K, const int N, const int rA, const int rB,
                 ushort_t* ls) {
    constexpr int WM = BM / WGM, WN = BN / WGN;
    constexpr int MI = WM / 16, NJ = WN / 16;
    constexpr int LA = (BM * 8) / THREADS;
    constexpr int LB = (BN * 8) / THREADS;
    constexpr int L  = LA + LB;
    constexpr int HALF = (BM + BN) * 64;

    const int tid  = threadIdx.x;
    const int lane = tid & 63;
    const int wv   = tid >> 6;
    const int wr   = wv / WGN, wc = wv % WGN;
    const int fr   = lane & 15, fq = lane >> 4;

    f32x4 acc[MI][NJ] = {};

    auto stage = [&](int k0, int buf) {
        #pragma unroll
        for (int q = 0; q < LA; ++q) {
            int c = q * THREADS + tid;
            int row = c >> 3;
            int u = (c & 7) ^ (row & 7);
            GLOAD_LDS16(A + (size_t)(rA + row) * K + k0 + u * 8,
                        &ls[buf * HALF + c * 8]);
        }
        #pragma unroll
        for (int q = 0; q < LB; ++q) {
            int c = q * THREADS + tid;
            int row = c >> 3;
            int u = (c & 7) ^ (row & 7);
            GLOAD_LDS16(B + (size_t)(rB + row) * K + k0 + u * 8,
                        &ls[buf * HALF + BM * 64 + c * 8]);
        }
    };

    auto compute = [&](int buf) {
        #pragma unroll
        for (int sub = 0; sub < 2; ++sub) {
            const int u = sub * 4 + fq;
            bf16x8 af[MI], bfv[NJ];
            #pragma unroll
            for (int i = 0; i < MI; ++i) {
                const int row = wr * WM + i * 16 + fr;
                af[i] = *(const bf16x8*)&ls[buf * HALF + row * 64 + (u ^ (row & 7)) * 8];
            }
            #pragma unroll
            for (int j = 0; j < NJ; ++j) {
                const int row = wc * WN + j * 16 + fr;
                bfv[j] = *(const bf16x8*)&ls[buf * HALF + BM * 64 + row * 64 + (u ^ (row & 7)) * 8];
            }
            #pragma unroll
            for (int i = 0; i < MI; ++i)
                #pragma unroll
                for (int j = 0; j < NJ; ++j)
                    acc[i][j] = __builtin_amdgcn_mfma_f32_16x16x32_bf16(af[i], bfv[j], acc[i][j], 0, 0, 0);
        }
    };

    const int T = K >> 6;
    stage(0, 0);
    stage(64, 1);
    int cur = 0, nxt2 = 2;
    for (int t = 0; t < T - 2; ++t) {
        stage((t + 2) << 6, nxt2);
        waitcnt_vm<2 * L>();
        __builtin_amdgcn_s_barrier(); CFENCE();
        compute(cur);
        LGKM0_SCHED();
        __builtin_amdgcn_s_barrier(); CFENCE();
        cur  = (cur  + 1 == 3) ? 0 : cur  + 1;
        nxt2 = (nxt2 + 1 == 3) ? 0 : nxt2 + 1;
    }
    waitcnt_vm<L>();
    __builtin_amdgcn_s_barrier(); CFENCE();
    compute(cur);
    cur = (cur + 1 == 3) ? 0 : cur + 1;
    LGKM0_SCHED();
    waitcnt_vm<0>();
    __builtin_amdgcn_s_barrier(); CFENCE();
    compute(cur);

    const int orow0 = rA + wr * WM + fq * 4;
    const int ocol0 = rB + wc * WN + fr;
    #pragma unroll
    for (int i = 0; i < MI; ++i)
        #pragma unroll
        for (int j = 0; j < NJ; ++j) {
            const int col = ocol0 + j * 16;
            const float bv = bias ? bias[col] : 0.f;
            #pragma unroll
            for (int r = 0; r < 4; ++r) {
                const int row = orow0 + i * 16 + r;
                const float v = acc[i][j][r] + bv;
                if constexpr (BF16_OUT)
                    ((ushort_t*)C)[(size_t)row * N + col] = f2bf(v);
                else
                    ((float*)C)[(size_t)row * N + col] = v;
            }
        }
}

// ---------------------------------------------------------------------------
// L1 prep (r8-exact): [0,128): w_out->bf16; [128,384): Pt[c][j] =
//     bf16(w_in[r(j)][c]); [384,640): bfused rows.
__global__ __launch_bounds__(256)
void prep(const float* __restrict__ w_in, const float* __restrict__ b_in,
          const float* __restrict__ w_out, const float* __restrict__ b_out,
          ushort_t* __restrict__ wob, ushort_t* __restrict__ Pt,
          float* __restrict__ bfused) {
    __shared__ ushort_t tile[64][65];
    const int b = blockIdx.x;
    const int t = threadIdx.x;

    if (b < 128) {
        #pragma unroll
        for (int p = 0; p < 8; ++p) {
            int i = b * 2048 + p * 256 + t;
            float4 v = ((const float4*)w_out)[i];
            ushort4 o; o.x = f2bf(v.x); o.y = f2bf(v.y); o.z = f2bf(v.z); o.w = f2bf(v.w);
            ((ushort4*)wob)[i] = o;
        }
    } else if (b < 384) {
        const int g = b - 128;
        const int gx = g & 15, gy = g >> 4;
        #pragma unroll
        for (int p = 0; p < 16; ++p) {
            int e = p * 256 + t;
            int j = e >> 6, c = e & 63;
            tile[j][c] = f2bf(w_in[(size_t)(gx * 192 + 128 + j) * 1024 + gy * 64 + c]);
        }
        __syncthreads();
        #pragma unroll
        for (int p = 0; p < 16; ++p) {
            int e = p * 256 + t;
            int c = e >> 6, j = e & 63;
            Pt[(size_t)(gy * 64 + c) * 1024 + gx * 64 + j] = tile[j][c];
        }
    } else {
        const int w = t >> 6, lane = t & 63;
        const int row = (b - 384) * 4 + w;
        float s = 0.f;
        #pragma unroll
        for (int it = 0; it < 16; ++it) {
            int j = it * 64 + lane;
            int r = (j >> 6) * 192 + 128 + (j & 63);
            s += w_out[(size_t)row * 1024 + j] * b_in[r];
        }
        #pragma unroll
        for (int off = 32; off; off >>= 1) s += __shfl_down(s, off, 64);
        if (lane == 0) bfused[row] = s + b_out[row];
    }
}

// ---------------------------------------------------------------------------
// L2 (r8-exact): [0,256): Wf = wob @ Pt^T (64x64 tiles, XCD-swizzled);
//     [256,768): x fp32 -> bf16 (overlaps the GEMM).
__global__ __launch_bounds__(256)
void k2(const ushort_t* __restrict__ wob, const ushort_t* __restrict__ Pt,
        ushort_t* __restrict__ Wfb,
        const float* __restrict__ x, ushort_t* __restrict__ xb) {
    __shared__ alignas(16) ushort_t ls[3 * (64 + 64) * 64];
    const int b = blockIdx.x;
    if (b < 256) {
        const int swz = (b & 7) * 32 + (b >> 3);
        const int by = swz >> 4, bx = swz & 15;
        gemm_core64<64, 64, 2, 2, 256, true>(wob, Pt, nullptr, (void*)Wfb, 1024, 1024,
                                             by * 64, bx * 64, ls);
    } else {
        const int g = b - 256;
        const int t = threadIdx.x;
        #pragma unroll
        for (int p = 0; p < 8; ++p) {
            int i = g * 2048 + p * 256 + t;
            float4 v = ((const float4*)x)[i];
            ushort4 o; o.x = f2bf(v.x); o.y = f2bf(v.y); o.z = f2bf(v.z); o.w = f2bf(v.w);
            ((ushort4*)xb)[i] = o;
        }
    }
}

// ---------------------------------------------------------------------------
// L3: out = xb @ Wfb^T + bfused. 128x128 tiles, 8 waves (2x4), 512 threads,
//     BK=128 DOUBLE-buffered (128 KB LDS, 1 block/CU): half the barriers of
//     the BK=64 tbuf version, same prefetch depth (8 VMEM ops in flight),
//     same conflict-free XOR swizzle (16 16B-units/row; XOR hits low 3 bits).
__global__ __launch_bounds__(512)
void k3(const ushort_t* __restrict__ xb, const ushort_t* __restrict__ Wfb,
        const float* __restrict__ bfused, float* __restrict__ out) {
    constexpr int HALF = (128 + 128) * 128;          // 32768 ushorts = 64 KB
    __shared__ alignas(16) ushort_t ls[2 * HALF];    // 128 KB
    const int b = blockIdx.x;
    const int swz = (b & 7) * 32 + (b >> 3);
    const int by = swz >> 3, bx = swz & 7;           // 32 M-tiles x 8 N-tiles
    const int rA = by * 128, rB = bx * 128;

    const int tid  = threadIdx.x;
    const int lane = tid & 63;
    const int wv   = tid >> 6;
    const int wr   = wv >> 2, wc = wv & 3;           // 2x4 waves: WM=64, WN=32
    const int fr   = lane & 15, fq = lane >> 4;

    f32x4 acc[4][2] = {};

    auto stage = [&](int k0, int buf) {
        #pragma unroll
        for (int q = 0; q < 4; ++q) {                // A: 128 rows x 16 chunks
            int c = q * 512 + tid;
            int row = c >> 4;
            int u = (c & 15) ^ (row & 7);            // pre-swizzled source unit
            GLOAD_LDS16(xb + (size_t)(rA + row) * 1024 + k0 + u * 8,
                        &ls[buf * HALF + c * 8]);
        }
        #pragma unroll
        for (int q = 0; q < 4; ++q) {                // B
            int c = q * 512 + tid;
            int row = c >> 4;
            int u = (c & 15) ^ (row & 7);
            GLOAD_LDS16(Wfb + (size_t)(rB + row) * 1024 + k0 + u * 8,
                        &ls[buf * HALF + 16384 + c * 8]);
        }
    };

    auto compute = [&](int buf) {
        #pragma unroll
        for (int sub = 0; sub < 4; ++sub) {          // K=128 -> 4 subs of 32
            const int u = sub * 4 + fq;
            bf16x8 af[4], bfv[2];
            #pragma unroll
            for (int i = 0; i < 4; ++i) {
                const int row = wr * 64 + i * 16 + fr;
                af[i] = *(const bf16x8*)&ls[buf * HALF + row * 128 + ((u ^ (row & 7))) * 8];
            }
            #pragma unroll
            for (int j = 0; j < 2; ++j) {
                const int row = wc * 32 + j * 16 + fr;
                bfv[j] = *(const bf16x8*)&ls[buf * HALF + 16384 + row * 128 + ((u ^ (row & 7))) * 8];
            }
            #pragma unroll
            for (int i = 0; i < 4; ++i)
                #pragma unroll
                for (int j = 0; j < 2; ++j)
                    acc[i][j] = __builtin_amdgcn_mfma_f32_16x16x32_bf16(af[i], bfv[j], acc[i][j], 0, 0, 0);
        }
    };

    stage(0, 0);                                     // 8 VMEM ops in flight
    int cur = 0;
    #pragma unroll 1
    for (int t = 0; t < 8; ++t) {                    // K=1024 / 128
        if (t < 7) {
            stage((t + 1) << 7, cur ^ 1);            // +8 ops -> 16 outstanding
            waitcnt_vm<8>();                         // tile t landed; t+1 in flight
        } else {
            waitcnt_vm<0>();
        }
        __builtin_amdgcn_s_barrier(); CFENCE();
        compute(cur);
        LGKM0_SCHED();                               // ds_reads drained before reuse
        __builtin_amdgcn_s_barrier(); CFENCE();
        cur ^= 1;
    }

    const int orow0 = rA + wr * 64 + fq * 4;
    const int ocol0 = rB + wc * 32 + fr;
    #pragma unroll
    for (int i = 0; i < 4; ++i)
        #pragma unroll
        for (int j = 0; j < 2; ++j) {
            const int col = ocol0 + j * 16;
            const float bv = bfused[col];
            #pragma unroll
            for (int r = 0; r < 4; ++r)
                out[(size_t)(orow0 + i * 16 + r) * 1024 + col] = acc[i][j][r] + bv;
        }
}

// ---------------------------------------------------------------------------
extern "C" void kernel_launch(void* const* d_in, const int* in_sizes, int n_in,
                              void* d_out, int out_size, void* d_ws, size_t ws_size,
                              hipStream_t stream) {
    const float* x     = (const float*)d_in[0];   // (2,2048,1024)
    const float* w_in  = (const float*)d_in[1];   // (3072,1024)
    const float* b_in  = (const float*)d_in[2];   // (3072,)
    const float* w_out = (const float*)d_in[3];   // (1024,1024)
    const float* b_out = (const float*)d_in[4];   // (1024,)
    float* out = (float*)d_out;                   // (2,2048,1024) fp32

    char* ws = (char*)d_ws;
    ushort_t* xb     = (ushort_t*)(ws);                      // 8 MB
    ushort_t* wob    = (ushort_t*)(ws + (8u  << 20));        // 2 MB
    ushort_t* Pt     = (ushort_t*)(ws + (10u << 20));        // 2 MB
    ushort_t* Wfb    = (ushort_t*)(ws + (12u << 20));        // 2 MB
    float*    bfused = (float*)   (ws + (14u << 20));        // 4 KB

    prep<<<640, 256, 0, stream>>>(w_in, b_in, w_out, b_out, wob, Pt, bfused);
    k2<<<768, 256, 0, stream>>>(wob, Pt, Wfb, x, xb);
    k3<<<256, 512, 0, stream>>>(xb, Wfb, bfused, out);
}

// Round 16
// 33.040 us; speedup vs baseline: 1.1233x; 1.0277x over previous
//
#include <hip/hip_runtime.h>

typedef unsigned short ushort_t;
typedef __bf16 bf16x8 __attribute__((ext_vector_type(8)));
typedef float f32x4 __attribute__((ext_vector_type(4)));

static __device__ __forceinline__ ushort_t f2bf(float f) {
    __bf16 b = (__bf16)f;   // RNE convert
    return __builtin_bit_cast(ushort_t, b);
}

#define GLOAD_LDS16(gptr, lptr)                                                        \
    __builtin_amdgcn_global_load_lds(                                                  \
        (const __attribute__((address_space(1))) void*)(gptr),                         \
        (__attribute__((address_space(3))) void*)(lptr), 16, 0, 0)

#define CFENCE() asm volatile("" ::: "memory")
#define LGKM0_SCHED() do { asm volatile("s_waitcnt lgkmcnt(0)" ::: "memory");          \
                           __builtin_amdgcn_sched_barrier(0); } while (0)

template <int N> __device__ __forceinline__ void waitcnt_vm() {
    if constexpr (N == 0)      asm volatile("s_waitcnt vmcnt(0)" ::: "memory");
    else if constexpr (N == 4) asm volatile("s_waitcnt vmcnt(4)" ::: "memory");
    else if constexpr (N == 8) asm volatile("s_waitcnt vmcnt(8)" ::: "memory");
}

// ---------------------------------------------------------------------------
// Triple-buffered, bank-conflict-free GEMM core (r8 exact).
// C[M][N] = A[M][K] @ B[N][K]^T (+bias), bf16 in. BK=64 (128B LDS rows).
// LDS layout: lds[row*64 + s*8 .. +8) = tile[row][ (s ^ (row&7))*8 .. +8 )
//   staged by global_load_lds with PRE-SWIZZLED global source (linear dest);
//   ds_read applies the same XOR -> 2 lanes/bank = conflict-free.
// Depth-2 counted-vmcnt prefetch: steady-state wait vmcnt(2L), never 0.
template <int BM, int BN, int WGM, int WGN, int THREADS, bool BF16_OUT>
__device__ __forceinline__
void gemm_core64(const ushort_t* __restrict__ A, const ushort_t* __restrict__ B,
                 const float* __restrict__ bias, void* __restrict__ C,
                 const int K, const int N, const int rA, const int rB,
                 ushort_t* ls) {
    constexpr int WM = BM / WGM, WN = BN / WGN;
    constexpr int MI = WM / 16, NJ = WN / 16;
    constexpr int LA = (BM * 8) / THREADS;      // 16B chunks per thread (A)
    constexpr int LB = (BN * 8) / THREADS;
    constexpr int L  = LA + LB;
    constexpr int HALF = (BM + BN) * 64;         // ushorts per buffer

    const int tid  = threadIdx.x;
    const int lane = tid & 63;
    const int wv   = tid >> 6;
    const int wr   = wv / WGN, wc = wv % WGN;
    const int fr   = lane & 15, fq = lane >> 4;

    f32x4 acc[MI][NJ] = {};

    auto stage = [&](int k0, int buf) {
        #pragma unroll
        for (int q = 0; q < LA; ++q) {
            int c = q * THREADS + tid;
            int row = c >> 3;
            int u = (c & 7) ^ (row & 7);         // pre-swizzled global 16B-unit
            GLOAD_LDS16(A + (size_t)(rA + row) * K + k0 + u * 8,
                        &ls[buf * HALF + c * 8]);
        }
        #pragma unroll
        for (int q = 0; q < LB; ++q) {
            int c = q * THREADS + tid;
            int row = c >> 3;
            int u = (c & 7) ^ (row & 7);
            GLOAD_LDS16(B + (size_t)(rB + row) * K + k0 + u * 8,
                        &ls[buf * HALF + BM * 64 + c * 8]);
        }
    };

    auto compute = [&](int buf) {
        #pragma unroll
        for (int sub = 0; sub < 2; ++sub) {
            const int u = sub * 4 + fq;
            bf16x8 af[MI], bfv[NJ];
            #pragma unroll
            for (int i = 0; i < MI; ++i) {
                const int row = wr * WM + i * 16 + fr;
                af[i] = *(const bf16x8*)&ls[buf * HALF + row * 64 + (u ^ (row & 7)) * 8];
            }
            #pragma unroll
            for (int j = 0; j < NJ; ++j) {
                const int row = wc * WN + j * 16 + fr;
                bfv[j] = *(const bf16x8*)&ls[buf * HALF + BM * 64 + row * 64 + (u ^ (row & 7)) * 8];
            }
            #pragma unroll
            for (int i = 0; i < MI; ++i)
                #pragma unroll
                for (int j = 0; j < NJ; ++j)
                    acc[i][j] = __builtin_amdgcn_mfma_f32_16x16x32_bf16(af[i], bfv[j], acc[i][j], 0, 0, 0);
        }
    };

    const int T = K >> 6;                        // BK=64; requires T >= 3
    stage(0, 0);
    stage(64, 1);
    int cur = 0, nxt2 = 2;
    for (int t = 0; t < T - 2; ++t) {
        stage((t + 2) << 6, nxt2);               // issue tile t+2
        waitcnt_vm<2 * L>();                     // tile t landed; t+1,t+2 in flight
        __builtin_amdgcn_s_barrier(); CFENCE();
        compute(cur);
        LGKM0_SCHED();                           // ds_reads complete before barrier
        __builtin_amdgcn_s_barrier(); CFENCE();
        cur  = (cur  + 1 == 3) ? 0 : cur  + 1;
        nxt2 = (nxt2 + 1 == 3) ? 0 : nxt2 + 1;
    }
    waitcnt_vm<L>();                             // tile T-2 landed
    __builtin_amdgcn_s_barrier(); CFENCE();
    compute(cur);
    cur = (cur + 1 == 3) ? 0 : cur + 1;
    LGKM0_SCHED();
    waitcnt_vm<0>();                             // tile T-1 landed
    __builtin_amdgcn_s_barrier(); CFENCE();
    compute(cur);

    const int orow0 = rA + wr * WM + fq * 4;
    const int ocol0 = rB + wc * WN + fr;
    #pragma unroll
    for (int i = 0; i < MI; ++i)
        #pragma unroll
        for (int j = 0; j < NJ; ++j) {
            const int col = ocol0 + j * 16;
            const float bv = bias ? bias[col] : 0.f;
            #pragma unroll
            for (int r = 0; r < 4; ++r) {
                const int row = orow0 + i * 16 + r;
                const float v = acc[i][j][r] + bv;
                if constexpr (BF16_OUT)
                    ((ushort_t*)C)[(size_t)row * N + col] = f2bf(v);
                else
                    ((float*)C)[(size_t)row * N + col] = v;
            }
        }
}

// ---------------------------------------------------------------------------
// L1 (r8 exact): [0,128): w_out->bf16; [128,384): Pt gather+transpose;
//     [384,640): bfused rows.
__global__ __launch_bounds__(256)
void prep(const float* __restrict__ w_in, const float* __restrict__ b_in,
          const float* __restrict__ w_out, const float* __restrict__ b_out,
          ushort_t* __restrict__ wob, ushort_t* __restrict__ Pt,
          float* __restrict__ bfused) {
    __shared__ ushort_t tile[64][65];
    const int b = blockIdx.x;
    const int t = threadIdx.x;

    if (b < 128) {
        #pragma unroll
        for (int p = 0; p < 8; ++p) {
            int i = b * 2048 + p * 256 + t;
            float4 v = ((const float4*)w_out)[i];
            ushort4 o; o.x = f2bf(v.x); o.y = f2bf(v.y); o.z = f2bf(v.z); o.w = f2bf(v.w);
            ((ushort4*)wob)[i] = o;
        }
    } else if (b < 384) {
        const int g = b - 128;
        const int gx = g & 15, gy = g >> 4;
        #pragma unroll
        for (int p = 0; p < 16; ++p) {
            int e = p * 256 + t;
            int j = e >> 6, c = e & 63;
            tile[j][c] = f2bf(w_in[(size_t)(gx * 192 + 128 + j) * 1024 + gy * 64 + c]);
        }
        __syncthreads();
        #pragma unroll
        for (int p = 0; p < 16; ++p) {
            int e = p * 256 + t;
            int c = e >> 6, j = e & 63;
            Pt[(size_t)(gy * 64 + c) * 1024 + gx * 64 + j] = tile[j][c];
        }
    } else {
        const int w = t >> 6, lane = t & 63;
        const int row = (b - 384) * 4 + w;
        float s = 0.f;
        #pragma unroll
        for (int it = 0; it < 16; ++it) {
            int j = it * 64 + lane;
            int r = (j >> 6) * 192 + 128 + (j & 63);
            s += w_out[(size_t)row * 1024 + j] * b_in[r];
        }
        #pragma unroll
        for (int off = 32; off; off >>= 1) s += __shfl_down(s, off, 64);
        if (lane == 0) bfused[row] = s + b_out[row];
    }
}

// ---------------------------------------------------------------------------
// L2 (r8 exact): [0,256): Wf = wob @ Pt^T (64x64 tiles, XCD-swizzled);
//     [256,768): x fp32 -> bf16 (independent, overlaps the GEMM).
__global__ __launch_bounds__(256)
void k2(const ushort_t* __restrict__ wob, const ushort_t* __restrict__ Pt,
        ushort_t* __restrict__ Wfb,
        const float* __restrict__ x, ushort_t* __restrict__ xb) {
    __shared__ alignas(16) ushort_t ls[3 * (64 + 64) * 64];
    const int b = blockIdx.x;
    if (b < 256) {
        const int swz = (b & 7) * 32 + (b >> 3);
        const int by = swz >> 4, bx = swz & 15;
        gemm_core64<64, 64, 2, 2, 256, true>(wob, Pt, nullptr, (void*)Wfb, 1024, 1024,
                                             by * 64, bx * 64, ls);
    } else {
        const int g = b - 256;
        const int t = threadIdx.x;
        #pragma unroll
        for (int p = 0; p < 8; ++p) {
            int i = g * 2048 + p * 256 + t;
            float4 v = ((const float4*)x)[i];
            ushort4 o; o.x = f2bf(v.x); o.y = f2bf(v.y); o.z = f2bf(v.z); o.w = f2bf(v.w);
            ((ushort4*)xb)[i] = o;
        }
    }
}

// ---------------------------------------------------------------------------
// L3 (r8 exact): out = xb @ Wfb^T + bfused. 128x128 tiles, 8 waves (2x4),
//     512 threads, 256 blocks (1/CU), BK=64 conflict-free triple-buffered
//     counted-vmcnt core, XCD-swizzled.
__global__ __launch_bounds__(512)
void k3(const ushort_t* __restrict__ xb, const ushort_t* __restrict__ Wfb,
        const float* __restrict__ bfused, float* __restrict__ out) {
    __shared__ alignas(16) ushort_t ls[3 * (128 + 128) * 64];   // 96 KB
    const int b = blockIdx.x;
    const int swz = (b & 7) * 32 + (b >> 3);
    const int by = swz >> 3, bx = swz & 7;      // 32 M-tiles x 8 N-tiles
    gemm_core64<128, 128, 2, 4, 512, false>(xb, Wfb, bfused, (void*)out, 1024, 1024,
                                            by * 128, bx * 128, ls);
}

// ---------------------------------------------------------------------------
extern "C" void kernel_launch(void* const* d_in, const int* in_sizes, int n_in,
                              void* d_out, int out_size, void* d_ws, size_t ws_size,
                              hipStream_t stream) {
    const float* x     = (const float*)d_in[0];   // (2,2048,1024)
    const float* w_in  = (const float*)d_in[1];   // (3072,1024)
    const float* b_in  = (const float*)d_in[2];   // (3072,)
    const float* w_out = (const float*)d_in[3];   // (1024,1024)
    const float* b_out = (const float*)d_in[4];   // (1024,)
    float* out = (float*)d_out;                   // (2,2048,1024) fp32

    char* ws = (char*)d_ws;
    ushort_t* xb     = (ushort_t*)(ws);                      // 8 MB
    ushort_t* wob    = (ushort_t*)(ws + (8u  << 20));        // 2 MB
    ushort_t* Pt     = (ushort_t*)(ws + (10u << 20));        // 2 MB
    ushort_t* Wfb    = (ushort_t*)(ws + (12u << 20));        // 2 MB
    float*    bfused = (float*)   (ws + (14u << 20));        // 4 KB

    prep<<<640, 256, 0, stream>>>(w_in, b_in, w_out, b_out, wob, Pt, bfused);
    k2<<<768, 256, 0, stream>>>(wob, Pt, Wfb, x, xb);
    k3<<<256, 512, 0, stream>>>(xb, Wfb, bfused, out);
}